// Round 1
// 299.272 us; speedup vs baseline: 1.8487x; 1.8487x over previous
//
#include <hip/hip_runtime.h>

// DynamicQuantizer: power-iteration score -> conditional rank-1 scale -> int4 fake-quant.
// X: [8192, 4096] f32. Output f32 same shape.
//
// ws layout (floats):
//   [0, 8192)       y      (N)
//   [8192, 12288)   v      (H)
//   [12288, 16384)  c      (H)  = lora_a * lora_b
//   [16384, 16400)  scalars:
//     0: sum y1^2 (atomicAdd)   1: sum y2^2 (atomicAdd)
//     8: sigma_sq (atomicAdd)   9: frob (atomicAdd)
//     10: max|X| bits (atomicMax uint)  11: max|X_adapt| bits
//     12: scale   13: add-delta flag
//
// Pipeline (normalizations folded as scalar multiplies, applied late):
//   y1 = X v0                       (rowdot<0,0>, accumulates sum y1^2)
//   v  = X^T (y1 / ||y1||)          (coldot, inv from scal[0])
//   y2 = (X v) / ||v||              (rowdot<1,0>: ||v|| computed in-block from staged v)
//   v  = X^T (y2 / ||y2||)          (coldot, inv from scal[1])
//   sigma^2 = sum((X v / ||v||)^2)  (rowdot<1,1>, fused frob + abs-maxes)

#define NR 8192
#define HC 4096
#define H4 (HC / 4)
#define EPSV 1e-8f

__global__ void compute_c_kernel(const float* __restrict__ a, const float* __restrict__ b,
                                 float* __restrict__ c) {
    int i = blockIdx.x * blockDim.x + threadIdx.x;
    if (i < HC) c[i] = a[i] * b[i];
}

// One wave per row. 4 waves/block, grid = NR/4.
// NORMV: compute inv = 1/max(||v||,eps) in-block from the staged v and apply to the row dot.
// FUSED: also accumulate frob, max|X|, max|X_adapt|, sigma^2 into scal[8..11].
// !FUSED: write y[row] and atomicAdd sum(y^2) into *ssy.
template <int NORMV, int FUSED>
__global__ __launch_bounds__(256) void rowdot_kernel(
    const float4* __restrict__ X4, const float4* __restrict__ v4,
    float* __restrict__ y, float* __restrict__ ssy_or_scal,
    const float4* __restrict__ c4) {
    __shared__ float4 vsh[H4];   // 16 KB staged v
    __shared__ float sm[16];
    const int t = threadIdx.x;
    const int lane = t & 63;
    const int wid = t >> 6;

    // Stage v into LDS; optionally accumulate ||v||^2 on the way.
    float ss = 0.f;
#pragma unroll
    for (int k = 0; k < 4; ++k) {
        float4 vv = v4[t + k * 256];
        vsh[t + k * 256] = vv;
        if (NORMV) ss += vv.x * vv.x + vv.y * vv.y + vv.z * vv.z + vv.w * vv.w;
    }
    if (NORMV) {
#pragma unroll
        for (int m = 32; m; m >>= 1) ss += __shfl_xor(ss, m);
        if (lane == 0) sm[wid] = ss;
    }
    __syncthreads();
    float inv = 1.0f;
    if (NORMV) inv = 1.0f / fmaxf(sqrtf(sm[0] + sm[1] + sm[2] + sm[3]), EPSV);

    const int row = blockIdx.x * 4 + wid;
    const float4* Xr = X4 + (size_t)row * H4;

    // Issue all 16 row loads up-front for MLP, then consume against LDS v.
    float4 xr[16];
#pragma unroll
    for (int j = 0; j < 16; ++j) xr[j] = Xr[lane + j * 64];

    float acc = 0.f, frob = 0.f, mx = 0.f, ma = 0.f;
#pragma unroll
    for (int j = 0; j < 16; ++j) {
        float4 x = xr[j];
        float4 vv = vsh[lane + j * 64];
        acc += x.x * vv.x + x.y * vv.y + x.z * vv.z + x.w * vv.w;
        if (FUSED) {
            float4 cc = c4[lane + j * 64];
            frob += x.x * x.x + x.y * x.y + x.z * x.z + x.w * x.w;
            mx = fmaxf(mx, fmaxf(fmaxf(fabsf(x.x), fabsf(x.y)),
                                 fmaxf(fabsf(x.z), fabsf(x.w))));
            float ax = x.x + (x.x * cc.x) * 0.5f;
            float ay = x.y + (x.y * cc.y) * 0.5f;
            float az = x.z + (x.z * cc.z) * 0.5f;
            float aw = x.w + (x.w * cc.w) * 0.5f;
            ma = fmaxf(ma, fmaxf(fmaxf(fabsf(ax), fabsf(ay)),
                                 fmaxf(fabsf(az), fabsf(aw))));
        }
    }

    // Wave-level dot reduction: no barriers.
#pragma unroll
    for (int m = 32; m; m >>= 1) acc += __shfl_xor(acc, m);
    float yr = acc * inv;

    if (!FUSED) {
        if (lane == 0) {
            y[row] = yr;
            sm[4 + wid] = yr * yr;
        }
        __syncthreads();
        if (t == 0) atomicAdd(ssy_or_scal, sm[4] + sm[5] + sm[6] + sm[7]);
    } else {
        float* scal = ssy_or_scal;
#pragma unroll
        for (int m = 32; m; m >>= 1) {
            frob += __shfl_xor(frob, m);
            mx = fmaxf(mx, __shfl_xor(mx, m));
            ma = fmaxf(ma, __shfl_xor(ma, m));
        }
        __syncthreads();  // sm[0..3] (inv partials) fully consumed before reuse
        if (lane == 0) {
            sm[wid] = frob;
            sm[4 + wid] = mx;
            sm[8 + wid] = ma;
            sm[12 + wid] = yr * yr;
        }
        __syncthreads();
        if (t == 0) {
            atomicAdd(&scal[9], sm[0] + sm[1] + sm[2] + sm[3]);
            atomicAdd(&scal[8], sm[12] + sm[13] + sm[14] + sm[15]);
            atomicMax(reinterpret_cast<unsigned*>(&scal[10]),
                      __float_as_uint(fmaxf(fmaxf(sm[4], sm[5]), fmaxf(sm[6], sm[7]))));
            atomicMax(reinterpret_cast<unsigned*>(&scal[11]),
                      __float_as_uint(fmaxf(fmaxf(sm[8], sm[9]), fmaxf(sm[10], sm[11]))));
        }
    }
}

// v[col] += sum over a 64-row chunk of X[r][col] * (y[r]*inv), float4 per thread.
// inv = 1/max(sqrt(*ssp), eps) computed from the folded sum-of-squares scalar.
__global__ __launch_bounds__(256) void coldot_kernel(
    const float4* __restrict__ X4, const float* __restrict__ y,
    const float* __restrict__ ssp, float* __restrict__ v) {
    __shared__ float us[64];
    const int t = threadIdx.x;
    const int c4i = blockIdx.x * 256 + t;  // float4 column index
    const int r0 = blockIdx.y * 64;
    if (t < 64) {
        float inv = 1.0f / fmaxf(sqrtf(*ssp), EPSV);
        us[t] = y[r0 + t] * inv;
    }
    __syncthreads();
    float4 acc = make_float4(0.f, 0.f, 0.f, 0.f);
    const float4* Xp = X4 + (size_t)r0 * H4 + c4i;
#pragma unroll 8
    for (int r = 0; r < 64; ++r) {
        float4 x = Xp[(size_t)r * H4];
        float u = us[r];
        acc.x += x.x * u;
        acc.y += x.y * u;
        acc.z += x.z * u;
        acc.w += x.w * u;
    }
    float* vp = v + 4 * c4i;
    atomicAdd(vp + 0, acc.x);
    atomicAdd(vp + 1, acc.y);
    atomicAdd(vp + 2, acc.z);
    atomicAdd(vp + 3, acc.w);
}

__global__ void finalize_kernel(float* __restrict__ scal) {
    float sig2 = scal[8];
    float frob = scal[9];
    float score = sig2 / (frob + EPSV);
    int flag = score > 0.35f ? 1 : 0;
    unsigned mb = reinterpret_cast<unsigned*>(scal)[flag ? 11 : 10];
    float mv = __uint_as_float(mb);
    scal[12] = (mv < EPSV) ? 1.0f : mv / 7.0f;
    scal[13] = (float)flag;
}

__global__ __launch_bounds__(256) void quant_kernel(
    const float* __restrict__ X, const float* __restrict__ c,
    const float* __restrict__ scal, float* __restrict__ out) {
    const float scale = scal[12];
    const bool flag = scal[13] != 0.0f;
    const size_t total4 = (size_t)NR * HC / 4;
    const float4* X4 = reinterpret_cast<const float4*>(X);
    const float4* C4 = reinterpret_cast<const float4*>(c);
    float4* O4 = reinterpret_cast<float4*>(out);
    for (size_t i = (size_t)blockIdx.x * blockDim.x + threadIdx.x; i < total4;
         i += (size_t)gridDim.x * blockDim.x) {
        float4 x = X4[i];
        if (flag) {
            float4 cc = C4[i & (H4 - 1)];
            x.x += (x.x * cc.x) * 0.5f;
            x.y += (x.y * cc.y) * 0.5f;
            x.z += (x.z * cc.z) * 0.5f;
            x.w += (x.w * cc.w) * 0.5f;
        }
        float4 o;
        o.x = fminf(fmaxf(rintf(x.x / scale), -8.f), 7.f) * scale;
        o.y = fminf(fmaxf(rintf(x.y / scale), -8.f), 7.f) * scale;
        o.z = fminf(fmaxf(rintf(x.z / scale), -8.f), 7.f) * scale;
        o.w = fminf(fmaxf(rintf(x.w / scale), -8.f), 7.f) * scale;
        O4[i] = o;
    }
}

extern "C" void kernel_launch(void* const* d_in, const int* in_sizes, int n_in,
                              void* d_out, int out_size, void* d_ws, size_t ws_size,
                              hipStream_t stream) {
    const float* X  = (const float*)d_in[0];
    const float* la = (const float*)d_in[1];
    const float* lb = (const float*)d_in[2];
    const float* v0 = (const float*)d_in[3];
    float* ws = (float*)d_ws;
    float* y    = ws;
    float* v    = ws + NR;
    float* c    = ws + NR + HC;
    float* scal = ws + NR + 2 * HC;
    float* out  = (float*)d_out;

    const float4* X4 = reinterpret_cast<const float4*>(X);

    hipMemsetAsync(scal, 0, 16 * sizeof(float), stream);
    hipMemsetAsync(v, 0, HC * sizeof(float), stream);
    compute_c_kernel<<<HC / 256, 256, 0, stream>>>(la, lb, c);

    // power iteration 1
    rowdot_kernel<0, 0><<<NR / 4, 256, 0, stream>>>(
        X4, reinterpret_cast<const float4*>(v0), y, &scal[0], nullptr);
    coldot_kernel<<<dim3(HC / 1024, NR / 64), 256, 0, stream>>>(X4, y, &scal[0], v);

    // power iteration 2 (rowdot normalizes v in-block; y2 ss folded into scal[1])
    rowdot_kernel<1, 0><<<NR / 4, 256, 0, stream>>>(
        X4, reinterpret_cast<const float4*>(v), y, &scal[1], nullptr);
    hipMemsetAsync(v, 0, HC * sizeof(float), stream);
    coldot_kernel<<<dim3(HC / 1024, NR / 64), 256, 0, stream>>>(X4, y, &scal[1], v);

    // sigma = ||X v_norm||, fused with frob + abs-maxes
    rowdot_kernel<1, 1><<<NR / 4, 256, 0, stream>>>(
        X4, reinterpret_cast<const float4*>(v), nullptr, scal,
        reinterpret_cast<const float4*>(c));
    finalize_kernel<<<1, 1, 0, stream>>>(scal);

    // fake-quant output pass
    quant_kernel<<<2048, 256, 0, stream>>>(X, c, scal, out);
}

// Round 2
// 155.012 us; speedup vs baseline: 3.5693x; 1.9306x over previous
//
#include <hip/hip_runtime.h>

// DynamicQuantizer: power-iteration score -> conditional rank-1 scale -> int4 fake-quant.
// X: [8192, 4096] f32. Output f32 same shape.
//
// Math restructure: normalize(X^T normalize(Xv)) == normalize(X^T X v) (positive scalar
// cancels), so each power iteration is ONE fused pass over X:
//   w1 = X^T (X v0)            (xtxv<0>, partials -> d_out, reduced -> w1)
//   w2 = X^T (X w1 / ||w1||)   (xtxv<1>, inv computed in-block from staged w1)
//   sigma^2 = ||X w2/||w2||||^2 (rowsig, fused frob + max|X| + max|X_adapt|)
// Output depends on the power iteration only through (score > 0.35) and, if set, the
// adapted absmax; the quant math itself is exact.
//
// ws layout (floats):
//   [0, 4096)      w1
//   [4096, 8192)   w2
//   [8192, 12288)  c = lora_a * lora_b
//   [12288, 12304) scalars: 8: sigma_sq  9: frob  10: max|X| bits  11: max|X_adapt| bits
//                           12: scale    13: add-delta flag
// d_out doubles as the per-block partial buffer (512 x 4096 f32 = 8 MB) until quant.

#define NR 8192
#define HC 4096
#define H4 (HC / 4)
#define EPSV 1e-8f
#define XB 512           // blocks for the fused passes
#define ROWS_PER_WAVE 4  // 512 blocks * 4 waves * 4 rows = 8192

__global__ void compute_c_kernel(const float* __restrict__ a, const float* __restrict__ b,
                                 float* __restrict__ c) {
    int i = blockIdx.x * blockDim.x + threadIdx.x;
    if (i < HC) c[i] = a[i] * b[i];
}

// Fused partial of X^T (X v * inv) over a 16-row chunk. One wave per row-group of 4,
// row register-resident (used for dot AND axpy). Partial written to part4[blockIdx].
template <int NORMIN>
__global__ __launch_bounds__(256, 1) void xtxv_kernel(
    const float4* __restrict__ X4, const float4* __restrict__ vin,
    float4* __restrict__ part4) {
    __shared__ float4 vsh[H4];    // 16 KB staged v
    __shared__ float4 wredA[H4];  // 16 KB  (waves 0,2)
    __shared__ float4 wredB[H4];  // 16 KB  (waves 1,3)
    __shared__ float smn[4];
    const int t = threadIdx.x;
    const int lane = t & 63;
    const int wid = t >> 6;

    // Stage v; optionally accumulate ||v||^2 for in-block normalization.
    float ss = 0.f;
#pragma unroll
    for (int k = 0; k < 4; ++k) {
        float4 vv = vin[t + k * 256];
        vsh[t + k * 256] = vv;
        if (NORMIN) ss += vv.x * vv.x + vv.y * vv.y + vv.z * vv.z + vv.w * vv.w;
    }
    if (NORMIN) {
#pragma unroll
        for (int m = 32; m; m >>= 1) ss += __shfl_xor(ss, m);
        if (lane == 0) smn[wid] = ss;
    }
    __syncthreads();
    float inv = 1.0f;
    if (NORMIN) inv = 1.0f / fmaxf(sqrtf(smn[0] + smn[1] + smn[2] + smn[3]), EPSV);

    float4 wa[16];
#pragma unroll
    for (int j = 0; j < 16; ++j) wa[j] = make_float4(0.f, 0.f, 0.f, 0.f);

    const int r0 = blockIdx.x * (4 * ROWS_PER_WAVE) + wid * ROWS_PER_WAVE;
    float4 cur[16], nxt[16];
    {
        const float4* Xr = X4 + (size_t)r0 * H4;
#pragma unroll
        for (int j = 0; j < 16; ++j) cur[j] = Xr[lane + j * 64];
    }
#pragma unroll
    for (int i = 0; i < ROWS_PER_WAVE; ++i) {
        if (i < ROWS_PER_WAVE - 1) {
            const float4* Xn = X4 + (size_t)(r0 + i + 1) * H4;
#pragma unroll
            for (int j = 0; j < 16; ++j) nxt[j] = Xn[lane + j * 64];
        }
        float acc = 0.f;
#pragma unroll
        for (int j = 0; j < 16; ++j) {
            float4 x = cur[j];
            float4 vv = vsh[lane + j * 64];
            acc += x.x * vv.x + x.y * vv.y + x.z * vv.z + x.w * vv.w;
        }
#pragma unroll
        for (int m = 32; m; m >>= 1) acc += __shfl_xor(acc, m);
        const float yr = acc * inv;
#pragma unroll
        for (int j = 0; j < 16; ++j) {
            wa[j].x += yr * cur[j].x;
            wa[j].y += yr * cur[j].y;
            wa[j].z += yr * cur[j].z;
            wa[j].w += yr * cur[j].w;
        }
        if (i < ROWS_PER_WAVE - 1) {
#pragma unroll
            for (int j = 0; j < 16; ++j) cur[j] = nxt[j];
        }
    }

    // Cross-wave reduce: waves 0/1 write A/B, waves 2/3 add into A/B, flush A+B.
    if (wid == 0) {
#pragma unroll
        for (int j = 0; j < 16; ++j) wredA[j * 64 + lane] = wa[j];
    } else if (wid == 1) {
#pragma unroll
        for (int j = 0; j < 16; ++j) wredB[j * 64 + lane] = wa[j];
    }
    __syncthreads();
    if (wid == 2) {
#pragma unroll
        for (int j = 0; j < 16; ++j) {
            float4 t0 = wredA[j * 64 + lane];
            t0.x += wa[j].x; t0.y += wa[j].y; t0.z += wa[j].z; t0.w += wa[j].w;
            wredA[j * 64 + lane] = t0;
        }
    } else if (wid == 3) {
#pragma unroll
        for (int j = 0; j < 16; ++j) {
            float4 t0 = wredB[j * 64 + lane];
            t0.x += wa[j].x; t0.y += wa[j].y; t0.z += wa[j].z; t0.w += wa[j].w;
            wredB[j * 64 + lane] = t0;
        }
    }
    __syncthreads();
    float4* dst = part4 + (size_t)blockIdx.x * H4;
#pragma unroll
    for (int k = 0; k < 4; ++k) {
        float4 a = wredA[t + k * 256];
        float4 b = wredB[t + k * 256];
        a.x += b.x; a.y += b.y; a.z += b.z; a.w += b.w;
        dst[t + k * 256] = a;
    }
}

// w[h] += sum_b part[b][h], 16 b-chunks of 32 per column (64K tiny atomics).
__global__ __launch_bounds__(256) void reduce_part_kernel(
    const float* __restrict__ part, float* __restrict__ w) {
    const int g = blockIdx.x * 256 + threadIdx.x;  // 256 blocks -> 65536 threads
    const int h = g & (HC - 1);
    const int chunk = g >> 12;  // 0..15
    float s = 0.f;
#pragma unroll 8
    for (int b = chunk * 32; b < chunk * 32 + 32; ++b) s += part[(size_t)b * HC + h];
    atomicAdd(&w[h], s);
}

// sigma^2 = sum_r (inv * dot(X[r], w2))^2, fused frob, max|X|, max|X_adapt|.
__global__ __launch_bounds__(256, 1) void rowsig_kernel(
    const float4* __restrict__ X4, const float4* __restrict__ vin,
    const float4* __restrict__ c4, float* __restrict__ scal) {
    __shared__ float4 vsh[H4];
    __shared__ float4 csh[H4];
    __shared__ float smn[4];
    __shared__ float sm[16];
    const int t = threadIdx.x;
    const int lane = t & 63;
    const int wid = t >> 6;

    float ss = 0.f;
#pragma unroll
    for (int k = 0; k < 4; ++k) {
        float4 vv = vin[t + k * 256];
        vsh[t + k * 256] = vv;
        csh[t + k * 256] = c4[t + k * 256];
        ss += vv.x * vv.x + vv.y * vv.y + vv.z * vv.z + vv.w * vv.w;
    }
#pragma unroll
    for (int m = 32; m; m >>= 1) ss += __shfl_xor(ss, m);
    if (lane == 0) smn[wid] = ss;
    __syncthreads();
    const float inv = 1.0f / fmaxf(sqrtf(smn[0] + smn[1] + smn[2] + smn[3]), EPSV);

    const int r0 = blockIdx.x * (4 * ROWS_PER_WAVE) + wid * ROWS_PER_WAVE;
    float4 cur[16], nxt[16];
    {
        const float4* Xr = X4 + (size_t)r0 * H4;
#pragma unroll
        for (int j = 0; j < 16; ++j) cur[j] = Xr[lane + j * 64];
    }
    float sig = 0.f, frob = 0.f, mx = 0.f, ma = 0.f;
#pragma unroll
    for (int i = 0; i < ROWS_PER_WAVE; ++i) {
        if (i < ROWS_PER_WAVE - 1) {
            const float4* Xn = X4 + (size_t)(r0 + i + 1) * H4;
#pragma unroll
            for (int j = 0; j < 16; ++j) nxt[j] = Xn[lane + j * 64];
        }
        float acc = 0.f;
#pragma unroll
        for (int j = 0; j < 16; ++j) {
            float4 x = cur[j];
            float4 vv = vsh[lane + j * 64];
            float4 cc = csh[lane + j * 64];
            acc += x.x * vv.x + x.y * vv.y + x.z * vv.z + x.w * vv.w;
            frob += x.x * x.x + x.y * x.y + x.z * x.z + x.w * x.w;
            mx = fmaxf(mx, fmaxf(fmaxf(fabsf(x.x), fabsf(x.y)),
                                 fmaxf(fabsf(x.z), fabsf(x.w))));
            float ax = x.x + (x.x * cc.x) * 0.5f;
            float ay = x.y + (x.y * cc.y) * 0.5f;
            float az = x.z + (x.z * cc.z) * 0.5f;
            float aw = x.w + (x.w * cc.w) * 0.5f;
            ma = fmaxf(ma, fmaxf(fmaxf(fabsf(ax), fabsf(ay)),
                                 fmaxf(fabsf(az), fabsf(aw))));
        }
#pragma unroll
        for (int m = 32; m; m >>= 1) acc += __shfl_xor(acc, m);
        const float yr = acc * inv;
        sig += yr * yr;  // wave-uniform
        if (i < ROWS_PER_WAVE - 1) {
#pragma unroll
            for (int j = 0; j < 16; ++j) cur[j] = nxt[j];
        }
    }
#pragma unroll
    for (int m = 32; m; m >>= 1) {
        frob += __shfl_xor(frob, m);
        mx = fmaxf(mx, __shfl_xor(mx, m));
        ma = fmaxf(ma, __shfl_xor(ma, m));
    }
    if (lane == 0) {
        sm[wid] = frob;
        sm[4 + wid] = mx;
        sm[8 + wid] = ma;
        sm[12 + wid] = sig;
    }
    __syncthreads();
    if (t == 0) {
        atomicAdd(&scal[9], sm[0] + sm[1] + sm[2] + sm[3]);
        atomicAdd(&scal[8], sm[12] + sm[13] + sm[14] + sm[15]);
        atomicMax(reinterpret_cast<unsigned*>(&scal[10]),
                  __float_as_uint(fmaxf(fmaxf(sm[4], sm[5]), fmaxf(sm[6], sm[7]))));
        atomicMax(reinterpret_cast<unsigned*>(&scal[11]),
                  __float_as_uint(fmaxf(fmaxf(sm[8], sm[9]), fmaxf(sm[10], sm[11]))));
    }
}

__global__ void finalize_kernel(float* __restrict__ scal) {
    float sig2 = scal[8];
    float frob = scal[9];
    float score = sig2 / (frob + EPSV);
    int flag = score > 0.35f ? 1 : 0;
    unsigned mb = reinterpret_cast<unsigned*>(scal)[flag ? 11 : 10];
    float mv = __uint_as_float(mb);
    scal[12] = (mv < EPSV) ? 1.0f : mv / 7.0f;
    scal[13] = (float)flag;
}

__global__ __launch_bounds__(256) void quant_kernel(
    const float* __restrict__ X, const float* __restrict__ c,
    const float* __restrict__ scal, float* __restrict__ out) {
    const float scale = scal[12];
    const bool flag = scal[13] != 0.0f;
    const size_t total4 = (size_t)NR * HC / 4;
    const float4* X4 = reinterpret_cast<const float4*>(X);
    const float4* C4 = reinterpret_cast<const float4*>(c);
    float4* O4 = reinterpret_cast<float4*>(out);
    for (size_t i = (size_t)blockIdx.x * blockDim.x + threadIdx.x; i < total4;
         i += (size_t)gridDim.x * blockDim.x) {
        float4 x = X4[i];
        if (flag) {
            float4 cc = C4[i & (H4 - 1)];
            x.x += (x.x * cc.x) * 0.5f;
            x.y += (x.y * cc.y) * 0.5f;
            x.z += (x.z * cc.z) * 0.5f;
            x.w += (x.w * cc.w) * 0.5f;
        }
        float4 o;
        o.x = fminf(fmaxf(rintf(x.x / scale), -8.f), 7.f) * scale;
        o.y = fminf(fmaxf(rintf(x.y / scale), -8.f), 7.f) * scale;
        o.z = fminf(fmaxf(rintf(x.z / scale), -8.f), 7.f) * scale;
        o.w = fminf(fmaxf(rintf(x.w / scale), -8.f), 7.f) * scale;
        O4[i] = o;
    }
}

extern "C" void kernel_launch(void* const* d_in, const int* in_sizes, int n_in,
                              void* d_out, int out_size, void* d_ws, size_t ws_size,
                              hipStream_t stream) {
    const float* X  = (const float*)d_in[0];
    const float* la = (const float*)d_in[1];
    const float* lb = (const float*)d_in[2];
    const float* v0 = (const float*)d_in[3];
    float* ws = (float*)d_ws;
    float* w1   = ws;
    float* w2   = ws + HC;
    float* c    = ws + 2 * HC;
    float* scal = ws + 3 * HC;
    float* out  = (float*)d_out;
    float* part = (float*)d_out;  // 512*4096 f32 = 8 MB scratch inside the 128 MB output

    const float4* X4 = reinterpret_cast<const float4*>(X);

    hipMemsetAsync(w1, 0, 2 * HC * sizeof(float), stream);   // w1 + w2
    hipMemsetAsync(scal, 0, 16 * sizeof(float), stream);
    compute_c_kernel<<<HC / 256, 256, 0, stream>>>(la, lb, c);

    // power iteration 1: w1 = X^T X v0
    xtxv_kernel<0><<<XB, 256, 0, stream>>>(
        X4, reinterpret_cast<const float4*>(v0), reinterpret_cast<float4*>(part));
    reduce_part_kernel<<<256, 256, 0, stream>>>(part, w1);

    // power iteration 2: w2 = X^T X (w1/||w1||)
    xtxv_kernel<1><<<XB, 256, 0, stream>>>(
        X4, reinterpret_cast<const float4*>(w1), reinterpret_cast<float4*>(part));
    reduce_part_kernel<<<256, 256, 0, stream>>>(part, w2);

    // sigma^2 + frob + abs-maxes in one pass
    rowsig_kernel<<<XB, 256, 0, stream>>>(
        X4, reinterpret_cast<const float4*>(w2), reinterpret_cast<const float4*>(c), scal);
    finalize_kernel<<<1, 1, 0, stream>>>(scal);

    // fake-quant output pass (overwrites the partial scratch)
    quant_kernel<<<2048, 256, 0, stream>>>(X, c, scal, out);
}